// Round 4
// baseline (443.356 us; speedup 1.0000x reference)
//
#include <hip/hip_runtime.h>
#include <hip/hip_bf16.h>

// GAT layer, N=8192, F=128.
//   k1: Wh = h@W -> WhT (bf16 [F][N]); u/v computed in-block (k0 folded);
//       e_src = (h@u)/ln2, e_dst = (h@v)/ln2 (pre-scaled for exp2 in k2).
//   k2: SEG=1 full-row fusion. 512 blocks x 16 rows. Per iter: 16x128 P strip
//       (exp2-weights -> XOR-swizzled LDS tile) @ WhT via MFMA bf16.
//       Denominator completes in-block (shfl reduce); division folded into
//       the epilogue; direct write to out. No numpart/denpart/k3.
//       Nontemporal coalesced adj stream, depth-2 adj/e prefetch,
//       double-buffered tile, 1 barrier/iter.
//
// ws: [0,2MB) WhT bf16 | e_src[8192] | e_dst[8192]

#define NN 8192
#define FF 128
#define ITERS (NN / 128)     // 64 strips of 128 cols

typedef __bf16 bf16x8 __attribute__((ext_vector_type(8)));
typedef float floatx4 __attribute__((ext_vector_type(4)));
typedef int   intx4  __attribute__((ext_vector_type(4)));

__device__ __forceinline__ unsigned short b2u(__bf16 x) {
    return __builtin_bit_cast(unsigned short, x);
}

// ---------------- k1 ----------------
__global__ __launch_bounds__(512) void k1_wh(const float* __restrict__ h,
                                             const float* __restrict__ W,
                                             const float* __restrict__ a,
                                             unsigned short* __restrict__ WhT,
                                             float* __restrict__ e_src,
                                             float* __restrict__ e_dst) {
    __shared__ float hL[32 * 132];
    __shared__ float wL[128 * 132];
    __shared__ float uL[128], vL[128];
    __shared__ unsigned short tL[128 * 40];

    int t = threadIdx.x;
    int i0 = blockIdx.x * 32;

    {   // h tile: 32 x 128, 8 floats/thread
        int row = t >> 4, c = (t & 15) * 8;
        const float4* s = (const float4*)&h[(i0 + row) * FF + c];
        float4* d = (float4*)&hL[row * 132 + c];
        d[0] = s[0]; d[1] = s[1];
    }
    {   // W: 128 x 128, 32 floats/thread
        int row = t >> 2, c = (t & 3) * 32;
        const float4* s = (const float4*)&W[row * FF + c];
        float4* d = (float4*)&wL[row * 132 + c];
        #pragma unroll
        for (int j = 0; j < 8; j++) d[j] = s[j];
    }
    __syncthreads();

    // fold k0: u = (W@a1)/ln2, v = (W@a2)/ln2 computed per block
    if (t < 256) {
        int k = t & 127;
        const float* ap = a + (t >> 7) * FF;
        float s = 0.f;
        for (int c = 0; c < 128; c += 4) {
            float4 w4 = *(const float4*)&wL[k * 132 + c];
            s = fmaf(w4.x, ap[c], s);     s = fmaf(w4.y, ap[c + 1], s);
            s = fmaf(w4.z, ap[c + 2], s); s = fmaf(w4.w, ap[c + 3], s);
        }
        (t < 128 ? uL : vL)[k] = s * 1.44269504f;
    }

    // main matmul: each thread 4 rows x 2 cols
    int r0 = (t & 7) * 4;
    int c0 = (t >> 3) * 2;
    float acc[4][2] = {};
    for (int k0 = 0; k0 < 128; k0 += 4) {
        float4 hr[4]; float2 wr[4];
        #pragma unroll
        for (int i = 0; i < 4; i++) hr[i] = *(const float4*)&hL[(r0 + i) * 132 + k0];
        #pragma unroll
        for (int i = 0; i < 4; i++) wr[i] = *(const float2*)&wL[(k0 + i) * 132 + c0];
        #pragma unroll
        for (int kj = 0; kj < 4; kj++) {
            #pragma unroll
            for (int ri = 0; ri < 4; ri++) {
                float hvv = ((const float*)&hr[ri])[kj];
                acc[ri][0] = fmaf(hvv, wr[kj].x, acc[ri][0]);
                acc[ri][1] = fmaf(hvv, wr[kj].y, acc[ri][1]);
            }
        }
    }
    #pragma unroll
    for (int ri = 0; ri < 4; ri++)
        #pragma unroll
        for (int cj = 0; cj < 2; cj++)
            tL[(c0 + cj) * 40 + r0 + ri] = b2u((__bf16)acc[ri][cj]);
    __syncthreads();

    if (t < 64) {
        int row = t & 31;
        const float* sv = (t < 32) ? uL : vL;
        float s = 0.f;
        for (int k = 0; k < 128; k += 4) {
            float4 h4 = *(const float4*)&hL[row * 132 + k];
            float4 s4 = *(const float4*)&sv[k];
            s = fmaf(h4.x, s4.x, s); s = fmaf(h4.y, s4.y, s);
            s = fmaf(h4.z, s4.z, s); s = fmaf(h4.w, s4.w, s);
        }
        (t < 32 ? e_src : e_dst)[i0 + row] = s;
    }
    {   // WhT store: 512 threads x 8 shorts
        int f = t & 127, part = t >> 7;
        const uint4* s = (const uint4*)&tL[f * 40 + part * 8];
        uint4* d = (uint4*)&WhT[f * NN + i0 + part * 8];
        *d = *s;
    }
}

// ---------------- k2 ----------------
__device__ __forceinline__ float mask_w(int a, float x) {
    // x is pre-scaled by 1/ln2; leaky commutes with positive scale
    float l = fmaxf(x, 0.2f * x);
    float e = __builtin_amdgcn_exp2f(l);
    return a > 0 ? e : 0.f;
}

__device__ __forceinline__ ushort4 pack4(float w0, float w1, float w2, float w3) {
    union { ushort4 u; __bf16 b[4]; } pk;
    pk.b[0] = (__bf16)w0; pk.b[1] = (__bf16)w1;
    pk.b[2] = (__bf16)w2; pk.b[3] = (__bf16)w3;
    return pk.u;
}

__global__ __launch_bounds__(512, 4) void k2_gat(const int* __restrict__ adj,
                                                 const unsigned short* __restrict__ WhT,
                                                 const float* __restrict__ e_src,
                                                 const float* __restrict__ e_dst,
                                                 float* __restrict__ out) {
    __shared__ unsigned short wt[2][16 * 128];  // XOR-swizzled P strips, 4 KB each
    __shared__ float esL[16];
    __shared__ float denL[16];

    int t = threadIdx.x;
    int i0 = blockIdx.x * 16;

    if (t < 16) esL[t] = e_src[i0 + t];

    int q  = t & 31;                  // col int4-group within 128-col strip
    int ii = t >> 5;                  // row 0..15
    int lane = t & 63, wave = t >> 6;
    int mrow = lane & 15, quad = lane >> 4;
    int n0 = wave * 16;               // f-group owned by this wave

    const unsigned short* Bb = WhT + (size_t)(n0 + mrow) * NN + quad * 8;
    const intx4* Ab = (const intx4*)(adj + (size_t)(i0 + ii) * NN + q * 4);
    const float* Eb = e_dst + q * 4;

    // swizzle: 8-col group gg stored at gg ^ (row & 7); row stride 128 shorts
    int waddr = ii * 128 + (((q >> 1) ^ (ii & 7)) << 3) + ((q & 1) << 2);
    int ra0 = mrow * 128 + (((0 + quad) ^ (mrow & 7)) << 3);
    int ra1 = mrow * 128 + (((4 + quad) ^ (mrow & 7)) << 3);
    int ra2 = mrow * 128 + (((8 + quad) ^ (mrow & 7)) << 3);
    int ra3 = mrow * 128 + (((12 + quad) ^ (mrow & 7)) << 3);

    floatx4 acc = {0.f, 0.f, 0.f, 0.f};
    float dsum = 0.f;

    // prologue: depth-2 adj/e prefetch (iter 0 and 1); 32 intx4 per 128-col step
    intx4  av0 = __builtin_nontemporal_load(Ab);
    float4 ed0 = *(const float4*)Eb;
    intx4  avB = __builtin_nontemporal_load(Ab + 32);
    float4 edB = *(const float4*)(Eb + 128);

    __syncthreads();
    float es_i = esL[ii];

    {
        float w0 = mask_w(av0.x, es_i + ed0.x);
        float w1 = mask_w(av0.y, es_i + ed0.y);
        float w2 = mask_w(av0.z, es_i + ed0.z);
        float w3 = mask_w(av0.w, es_i + ed0.w);
        dsum += (w0 + w1) + (w2 + w3);
        *(ushort4*)&wt[0][waddr] = pack4(w0, w1, w2, w3);
    }
    __syncthreads();

    for (int k = 0; k < ITERS - 1; k++) {
        // prefetch iteration k+2 (clamped -> always in-bounds, branchless)
        int jp = ((k + 2 < ITERS) ? (k + 2) : (ITERS - 1));
        intx4  avN = __builtin_nontemporal_load(Ab + jp * 32);
        float4 edN = *(const float4*)(Eb + jp * 128);

        // B fragments for iteration k (L2-resident WhT, hidden under VALU)
        int j0 = k * 128;
        bf16x8 b0 = *(const bf16x8*)(Bb + j0);
        bf16x8 b1 = *(const bf16x8*)(Bb + j0 + 32);
        bf16x8 b2 = *(const bf16x8*)(Bb + j0 + 64);
        bf16x8 b3 = *(const bf16x8*)(Bb + j0 + 96);

        // MFMA on iteration k
        const unsigned short* buf = wt[k & 1];
        bf16x8 a0 = *(const bf16x8*)&buf[ra0];
        bf16x8 a1 = *(const bf16x8*)&buf[ra1];
        bf16x8 a2 = *(const bf16x8*)&buf[ra2];
        bf16x8 a3 = *(const bf16x8*)&buf[ra3];
        acc = __builtin_amdgcn_mfma_f32_16x16x32_bf16(a0, b0, acc, 0, 0, 0);
        acc = __builtin_amdgcn_mfma_f32_16x16x32_bf16(a1, b1, acc, 0, 0, 0);
        acc = __builtin_amdgcn_mfma_f32_16x16x32_bf16(a2, b2, acc, 0, 0, 0);
        acc = __builtin_amdgcn_mfma_f32_16x16x32_bf16(a3, b3, acc, 0, 0, 0);

        // compute iteration k+1 weights -> other buffer (uses depth-2 slot)
        float w0 = mask_w(avB.x, es_i + edB.x);
        float w1 = mask_w(avB.y, es_i + edB.y);
        float w2 = mask_w(avB.z, es_i + edB.z);
        float w3 = mask_w(avB.w, es_i + edB.w);
        dsum += (w0 + w1) + (w2 + w3);
        *(ushort4*)&wt[(k + 1) & 1][waddr] = pack4(w0, w1, w2, w3);
        avB = avN; edB = edN;
        __syncthreads();
    }
    {
        int j0 = (ITERS - 1) * 128;
        bf16x8 b0 = *(const bf16x8*)(Bb + j0);
        bf16x8 b1 = *(const bf16x8*)(Bb + j0 + 32);
        bf16x8 b2 = *(const bf16x8*)(Bb + j0 + 64);
        bf16x8 b3 = *(const bf16x8*)(Bb + j0 + 96);
        const unsigned short* buf = wt[(ITERS - 1) & 1];
        bf16x8 a0 = *(const bf16x8*)&buf[ra0];
        bf16x8 a1 = *(const bf16x8*)&buf[ra1];
        bf16x8 a2 = *(const bf16x8*)&buf[ra2];
        bf16x8 a3 = *(const bf16x8*)&buf[ra3];
        acc = __builtin_amdgcn_mfma_f32_16x16x32_bf16(a0, b0, acc, 0, 0, 0);
        acc = __builtin_amdgcn_mfma_f32_16x16x32_bf16(a1, b1, acc, 0, 0, 0);
        acc = __builtin_amdgcn_mfma_f32_16x16x32_bf16(a2, b2, acc, 0, 0, 0);
        acc = __builtin_amdgcn_mfma_f32_16x16x32_bf16(a3, b3, acc, 0, 0, 0);
    }

    // denominator: full row sum completes in-block. 32 q-threads per row are
    // one contiguous half-wave -> xor-shuffle reduce within 32 lanes.
    dsum += __shfl_xor(dsum, 16);
    dsum += __shfl_xor(dsum, 8);
    dsum += __shfl_xor(dsum, 4);
    dsum += __shfl_xor(dsum, 2);
    dsum += __shfl_xor(dsum, 1);
    if (q == 0) denL[ii] = 1.0f / dsum;
    __syncthreads();

    // epilogue: divide and write directly to out.
    // C/D layout col=lane&15 (f), row=(lane>>4)*4+reg (i)
    #pragma unroll
    for (int r = 0; r < 4; r++) {
        int row0 = quad * 4 + r;
        out[(size_t)(i0 + row0) * FF + n0 + mrow] = acc[r] * denL[row0];
    }
}

extern "C" void kernel_launch(void* const* d_in, const int* in_sizes, int n_in,
                              void* d_out, int out_size, void* d_ws, size_t ws_size,
                              hipStream_t stream) {
    const float* h   = (const float*)d_in[0];
    const int*   adj = (const int*)d_in[1];
    const float* W   = (const float*)d_in[2];
    const float* a   = (const float*)d_in[3];
    float* out = (float*)d_out;

    char* ws = (char*)d_ws;
    unsigned short* WhT = (unsigned short*)ws;              // 2 MB bf16 [F][N]
    float* e_src = (float*)(ws + 2097152);
    float* e_dst = e_src + NN;

    k1_wh<<<dim3(256), dim3(512), 0, stream>>>(h, W, a, WhT, e_src, e_dst);
    k2_gat<<<dim3(NN / 16), dim3(512), 0, stream>>>(adj, WhT, e_src, e_dst, out);
}

// Round 5
// 399.296 us; speedup vs baseline: 1.1103x; 1.1103x over previous
//
#include <hip/hip_runtime.h>
#include <hip/hip_bf16.h>

// GAT layer, N=8192, F=128.  (revert of round-4's SEG=1 regression; this is
// the round-3 structure + nontemporal hints on single-use streams)
//   k1: Wh = h@W -> WhT (bf16 [F][N]); u/v computed in-block (k0 folded);
//       e_src = (h@u)/ln2, e_dst = (h@v)/ln2 (pre-scaled for exp2 in k2).
//   k2: fused masked-softmax(P) @ Wh via MFMA bf16, j split 4-ways across
//       blocks; atomic-free per-seg numpart/denpart slabs; coalesced
//       nontemporal adj reads, depth-2 adj/e prefetch, depth-1 B prefetch,
//       two independent acc chains, double-buffered XOR-swizzled P tile,
//       1 barrier/iter; exp2 + packed bf16 cvt.
//   k3: out[i][:] = (sum_seg numpart)/(sum_seg denpart), nontemporal slab reads
//
// ws: [0,2MB) WhT bf16 | e_src[8192] | e_dst[8192] | denpart[4*8192]
//     | [4MB,20MB) numpart[4][8192][128]

#define NN 8192
#define FF 128
#define SEG 4
#define JSEG (NN / SEG)      // 2048
#define ITERS (JSEG / 64)    // 32

typedef __bf16 bf16x8 __attribute__((ext_vector_type(8)));
typedef float floatx4 __attribute__((ext_vector_type(4)));
typedef int   intx4  __attribute__((ext_vector_type(4)));
typedef float fx4    __attribute__((ext_vector_type(4)));

__device__ __forceinline__ unsigned short b2u(__bf16 x) {
    return __builtin_bit_cast(unsigned short, x);
}

// ---------------- k1 ----------------
__global__ __launch_bounds__(512) void k1_wh(const float* __restrict__ h,
                                             const float* __restrict__ W,
                                             const float* __restrict__ a,
                                             unsigned short* __restrict__ WhT,
                                             float* __restrict__ e_src,
                                             float* __restrict__ e_dst) {
    __shared__ float hL[32 * 132];
    __shared__ float wL[128 * 132];
    __shared__ float uL[128], vL[128];
    __shared__ unsigned short tL[128 * 40];

    int t = threadIdx.x;
    int i0 = blockIdx.x * 32;

    {   // h tile: 32 x 128, 8 floats/thread (single-use stream -> nontemporal)
        int row = t >> 4, c = (t & 15) * 8;
        const fx4* s = (const fx4*)&h[(i0 + row) * FF + c];
        fx4 v0 = __builtin_nontemporal_load(s);
        fx4 v1 = __builtin_nontemporal_load(s + 1);
        *(fx4*)&hL[row * 132 + c] = v0;
        *(fx4*)&hL[row * 132 + c + 4] = v1;
    }
    {   // W: 128 x 128, 32 floats/thread (reused across blocks -> cached)
        int row = t >> 2, c = (t & 3) * 32;
        const float4* s = (const float4*)&W[row * FF + c];
        float4* d = (float4*)&wL[row * 132 + c];
        #pragma unroll
        for (int j = 0; j < 8; j++) d[j] = s[j];
    }
    __syncthreads();

    // fold k0: u = (W@a1)/ln2, v = (W@a2)/ln2 computed per block
    if (t < 256) {
        int k = t & 127;
        const float* ap = a + (t >> 7) * FF;
        float s = 0.f;
        for (int c = 0; c < 128; c += 4) {
            float4 w4 = *(const float4*)&wL[k * 132 + c];
            s = fmaf(w4.x, ap[c], s);     s = fmaf(w4.y, ap[c + 1], s);
            s = fmaf(w4.z, ap[c + 2], s); s = fmaf(w4.w, ap[c + 3], s);
        }
        (t < 128 ? uL : vL)[k] = s * 1.44269504f;
    }

    // main matmul: each thread 4 rows x 2 cols
    int r0 = (t & 7) * 4;
    int c0 = (t >> 3) * 2;
    float acc[4][2] = {};
    for (int k0 = 0; k0 < 128; k0 += 4) {
        float4 hr[4]; float2 wr[4];
        #pragma unroll
        for (int i = 0; i < 4; i++) hr[i] = *(const float4*)&hL[(r0 + i) * 132 + k0];
        #pragma unroll
        for (int i = 0; i < 4; i++) wr[i] = *(const float2*)&wL[(k0 + i) * 132 + c0];
        #pragma unroll
        for (int kj = 0; kj < 4; kj++) {
            #pragma unroll
            for (int ri = 0; ri < 4; ri++) {
                float hvv = ((const float*)&hr[ri])[kj];
                acc[ri][0] = fmaf(hvv, wr[kj].x, acc[ri][0]);
                acc[ri][1] = fmaf(hvv, wr[kj].y, acc[ri][1]);
            }
        }
    }
    #pragma unroll
    for (int ri = 0; ri < 4; ri++)
        #pragma unroll
        for (int cj = 0; cj < 2; cj++)
            tL[(c0 + cj) * 40 + r0 + ri] = b2u((__bf16)acc[ri][cj]);
    __syncthreads();

    if (t < 64) {
        int row = t & 31;
        const float* sv = (t < 32) ? uL : vL;
        float s = 0.f;
        for (int k = 0; k < 128; k += 4) {
            float4 h4 = *(const float4*)&hL[row * 132 + k];
            float4 s4 = *(const float4*)&sv[k];
            s = fmaf(h4.x, s4.x, s); s = fmaf(h4.y, s4.y, s);
            s = fmaf(h4.z, s4.z, s); s = fmaf(h4.w, s4.w, s);
        }
        (t < 32 ? e_src : e_dst)[i0 + row] = s;
    }
    {   // WhT store: 512 threads x 8 shorts
        int f = t & 127, part = t >> 7;
        const uint4* s = (const uint4*)&tL[f * 40 + part * 8];
        uint4* d = (uint4*)&WhT[f * NN + i0 + part * 8];
        *d = *s;
    }
}

// ---------------- k2 ----------------
__device__ __forceinline__ float mask_w(int a, float x) {
    // x is pre-scaled by 1/ln2; leaky commutes with positive scale
    float l = fmaxf(x, 0.2f * x);
    float e = __builtin_amdgcn_exp2f(l);
    return a > 0 ? e : 0.f;
}

__device__ __forceinline__ ushort4 pack4(float w0, float w1, float w2, float w3) {
    union { ushort4 u; __bf16 b[4]; } pk;
    pk.b[0] = (__bf16)w0; pk.b[1] = (__bf16)w1;
    pk.b[2] = (__bf16)w2; pk.b[3] = (__bf16)w3;
    return pk.u;
}

__global__ __launch_bounds__(512, 4) void k2_gat(const int* __restrict__ adj,
                                                 const unsigned short* __restrict__ WhT,
                                                 const float* __restrict__ e_src,
                                                 const float* __restrict__ e_dst,
                                                 float* __restrict__ numpart,
                                                 float* __restrict__ denpart) {
    __shared__ unsigned short wt[2][32 * 64];   // XOR-swizzled P tiles, 4 KB each
    __shared__ float esL[32];
    __shared__ float dpart[32 * 17];

    int t = threadIdx.x;
    int bx = blockIdx.x;
    int g = bx >> 2, seg = bx & 3;
    int i0 = g * 32;
    int jbase = seg * JSEG;

    if (t < 32) esL[t] = e_src[i0 + t];

    // coalesced mapping: 16 consecutive lanes sweep one row's 64 cols
    int q  = t & 15;                  // col-group (int4)
    int ii = t >> 4;                  // row 0..31
    int lane = t & 63, wave = t >> 6;
    int mrow = lane & 15, quad = lane >> 4;
    int n0 = wave * 16;

    const unsigned short* Bb = WhT + (size_t)(n0 + mrow) * NN + jbase + quad * 8;
    const intx4* Ab = (const intx4*)(adj + (size_t)(i0 + ii) * NN + jbase + q * 4);
    const float* Eb = e_dst + jbase + q * 4;

    // swizzled addresses (shorts): 8-col group gg stored at gg ^ (row & 7)
    int waddr = ii * 64 + (((q >> 1) ^ (ii & 7)) << 3) + ((q & 1) << 2);
    int ra00 = mrow * 64 + ((quad ^ (mrow & 7)) << 3);
    int ra01 = mrow * 64 + (((4 + quad) ^ (mrow & 7)) << 3);
    int ra10 = (16 + mrow) * 64 + ((quad ^ (mrow & 7)) << 3);
    int ra11 = (16 + mrow) * 64 + (((4 + quad) ^ (mrow & 7)) << 3);

    floatx4 acc0 = {0.f, 0.f, 0.f, 0.f};
    floatx4 acc1 = {0.f, 0.f, 0.f, 0.f};
    float dsum = 0.f;

    // prologue: adj/e depth-2 prefetch; B fragments for iter 0.
    // Ab is intx4*: one 64-col iter step = 16 intx4.
    intx4  av0 = __builtin_nontemporal_load(Ab);
    float4 ed0 = *(const float4*)Eb;
    intx4  avB = __builtin_nontemporal_load(Ab + 16);
    float4 edB = *(const float4*)(Eb + 64);
    bf16x8 b0 = *(const bf16x8*)Bb;
    bf16x8 b1 = *(const bf16x8*)(Bb + 32);

    __syncthreads();
    float es_i = esL[ii];

    {
        float w0 = mask_w(av0.x, es_i + ed0.x);
        float w1 = mask_w(av0.y, es_i + ed0.y);
        float w2 = mask_w(av0.z, es_i + ed0.z);
        float w3 = mask_w(av0.w, es_i + ed0.w);
        dsum += (w0 + w1) + (w2 + w3);
        *(ushort4*)&wt[0][waddr] = pack4(w0, w1, w2, w3);
    }
    __syncthreads();

    for (int k = 0; k < ITERS - 1; k++) {
        // prefetch iteration k+2 (clamped -> always in-bounds, branchless)
        int jp = ((k + 2 < ITERS) ? (k + 2) : (ITERS - 1));
        intx4  avN = __builtin_nontemporal_load(Ab + jp * 16);
        float4 edN = *(const float4*)(Eb + jp * 64);
        int jn = (k + 1) * 64;
        bf16x8 nb0 = *(const bf16x8*)(Bb + jn);
        bf16x8 nb1 = *(const bf16x8*)(Bb + jn + 32);

        // MFMA on iteration k (two independent acc chains)
        const unsigned short* buf = wt[k & 1];
        bf16x8 a00 = *(const bf16x8*)&buf[ra00];
        bf16x8 a10 = *(const bf16x8*)&buf[ra10];
        bf16x8 a01 = *(const bf16x8*)&buf[ra01];
        bf16x8 a11 = *(const bf16x8*)&buf[ra11];
        acc0 = __builtin_amdgcn_mfma_f32_16x16x32_bf16(a00, b0, acc0, 0, 0, 0);
        acc1 = __builtin_amdgcn_mfma_f32_16x16x32_bf16(a10, b0, acc1, 0, 0, 0);
        acc0 = __builtin_amdgcn_mfma_f32_16x16x32_bf16(a01, b1, acc0, 0, 0, 0);
        acc1 = __builtin_amdgcn_mfma_f32_16x16x32_bf16(a11, b1, acc1, 0, 0, 0);

        // compute iteration k+1 weights -> other buffer (uses depth-2 slot)
        float w0 = mask_w(avB.x, es_i + edB.x);
        float w1 = mask_w(avB.y, es_i + edB.y);
        float w2 = mask_w(avB.z, es_i + edB.z);
        float w3 = mask_w(avB.w, es_i + edB.w);
        dsum += (w0 + w1) + (w2 + w3);
        *(ushort4*)&wt[(k + 1) & 1][waddr] = pack4(w0, w1, w2, w3);
        avB = avN; edB = edN;
        b0 = nb0; b1 = nb1;
        __syncthreads();
    }
    {
        const unsigned short* buf = wt[(ITERS - 1) & 1];
        bf16x8 a00 = *(const bf16x8*)&buf[ra00];
        bf16x8 a10 = *(const bf16x8*)&buf[ra10];
        bf16x8 a01 = *(const bf16x8*)&buf[ra01];
        bf16x8 a11 = *(const bf16x8*)&buf[ra11];
        acc0 = __builtin_amdgcn_mfma_f32_16x16x32_bf16(a00, b0, acc0, 0, 0, 0);
        acc1 = __builtin_amdgcn_mfma_f32_16x16x32_bf16(a10, b0, acc1, 0, 0, 0);
        acc0 = __builtin_amdgcn_mfma_f32_16x16x32_bf16(a01, b1, acc0, 0, 0, 0);
        acc1 = __builtin_amdgcn_mfma_f32_16x16x32_bf16(a11, b1, acc1, 0, 0, 0);
    }

    dpart[ii * 17 + q] = dsum;
    __syncthreads();
    if (t < 32) {
        float s = 0.f;
        #pragma unroll
        for (int k = 0; k < 16; k++) s += dpart[t * 17 + k];
        __builtin_nontemporal_store(s, &denpart[seg * NN + i0 + t]);
    }

    // numerator: plain per-seg stores (no atomics; block owns its slab)
    // C/D layout col=lane&15, row=(lane>>4)*4+reg
    float* np = numpart + (size_t)seg * NN * FF;
    #pragma unroll
    for (int r = 0; r < 4; r++) {
        int row0 = quad * 4 + r;
        __builtin_nontemporal_store(acc0[r], &np[(size_t)(i0 + row0) * FF + n0 + mrow]);
        __builtin_nontemporal_store(acc1[r], &np[(size_t)(i0 + 16 + row0) * FF + n0 + mrow]);
    }
}

// ---------------- k3: out[i][:] = sum_seg(num)/sum_seg(den) ----------------
__global__ __launch_bounds__(256) void k3_merge(const float* __restrict__ np,
                                               const float* __restrict__ dp,
                                               float* __restrict__ out) {
    int idx = blockIdx.x * 256 + threadIdx.x;   // one float4 each
    int i = idx >> 5;
    int c = (idx & 31) << 2;
    float d = dp[i] + dp[NN + i] + dp[2 * NN + i] + dp[3 * NN + i];
    float r = 1.0f / d;
    size_t o = (size_t)i * FF + c;
    const size_t S = (size_t)NN * FF;
    fx4 a0 = __builtin_nontemporal_load((const fx4*)&np[o]);
    fx4 a1 = __builtin_nontemporal_load((const fx4*)&np[o + S]);
    fx4 a2 = __builtin_nontemporal_load((const fx4*)&np[o + 2 * S]);
    fx4 a3 = __builtin_nontemporal_load((const fx4*)&np[o + 3 * S]);
    fx4 v = ((a0 + a1) + (a2 + a3)) * r;
    __builtin_nontemporal_store(v, (fx4*)&out[o]);
}

extern "C" void kernel_launch(void* const* d_in, const int* in_sizes, int n_in,
                              void* d_out, int out_size, void* d_ws, size_t ws_size,
                              hipStream_t stream) {
    const float* h   = (const float*)d_in[0];
    const int*   adj = (const int*)d_in[1];
    const float* W   = (const float*)d_in[2];
    const float* a   = (const float*)d_in[3];
    float* out = (float*)d_out;

    char* ws = (char*)d_ws;
    unsigned short* WhT = (unsigned short*)ws;              // 2 MB bf16 [F][N]
    float* e_src = (float*)(ws + 2097152);
    float* e_dst = e_src + NN;
    float* denpart = e_dst + NN;                            // 4*NN floats = 128 KB
    float* numpart = (float*)(ws + (4u << 20));             // [4MB,20MB) 4*N*F

    k1_wh<<<dim3(256), dim3(512), 0, stream>>>(h, W, a, WhT, e_src, e_dst);
    k2_gat<<<dim3(256 * SEG), dim3(512), 0, stream>>>(adj, WhT, e_src, e_dst, numpart, denpart);
    k3_merge<<<dim3(NN * FF / 4 / 256), dim3(256), 0, stream>>>(numpart, denpart, out);
}